// Round 24
// baseline (391.927 us; speedup 1.0000x reference)
//
#include <hip/hip_runtime.h>
#include <math.h>

#define SB 8192
#define NB 32
#define WC 64
#define NM 16
#define NKC 32   // 2*NM (cos,sin interleaved)
#define NP 24
#define LP 132   // padded LDS row length (128 + 4)

// h layout: h[b][ch][s] (s contiguous)
// ws layout (float offsets):
//   h    : 0         (B*W*S = 16777216)
//   T    : 16777216  (S*32  = 262144)
//   xf   : 17039360  (B*W*32 = 65536)
//   ofT  : 17104896  (B*32*W = 65536)   [j][o] transposed mode weights
//   icaT : 17170432  (128*24 = 3072)
//   pwT  : 17173504  (4*64*64 = 16384)  [l][k][o] transposed pointwise weights
// DFT partials (64 slices x 32 b x 2048) live in the tc output region
// (dead until k_final). All layers produce them fused (lift for l=0,
// update for l=1..3).

__global__ __launch_bounds__(256) void k_table(float* __restrict__ T) {
    int s = blockIdx.x * 256 + threadIdx.x;   // exactly 8192 threads
    float* row = T + (size_t)s * NKC;
    #pragma unroll
    for (int k = 0; k < NM; ++k) {
        int m = (k * s) & (SB - 1);           // exact phase mod S
        double ang = (double)m * (6.283185307179586476925286766559 / (double)SB);
        row[2 * k]     = (float)cos(ang);
        row[2 * k + 1] = (float)sin(ang);
    }
}

// icaT[c][p] = fc2_w[0][c] * ica_w[p][c]
__global__ __launch_bounds__(256) void k_prep(const float* __restrict__ ica_w,
                                              const float* __restrict__ fc2_w,
                                              float* __restrict__ icaT) {
    int tid = blockIdx.x * 256 + threadIdx.x;   // exactly 3072
    int c = tid / NP;
    int p = tid - c * NP;
    icaT[c * NP + p] = ica_w[p * 128 + c] * fc2_w[c];
}

// pwT[l][k][o] = pw_w[l][o][k]
__global__ __launch_bounds__(256) void k_prepw(const float* __restrict__ pw_w,
                                               float* __restrict__ pwT) {
    int tid = blockIdx.x * 256 + threadIdx.x;   // exactly 16384
    int l = tid >> 12, k = (tid >> 6) & 63, o = tid & 63;
    pwT[tid] = pw_w[(size_t)l * 4096 + o * 64 + k];
}

// fused lift + forward DFT (round-21/18 v1 form: T staged in LDS).
__global__ __launch_bounds__(256) void k_lift(const float* __restrict__ x,
                                              const float* __restrict__ fc0_w,
                                              const float* __restrict__ fc0_b,
                                              float* __restrict__ h,
                                              const float* __restrict__ T,
                                              float* __restrict__ xfp) {
    __shared__ float u[12544];     // 50176 B: hT2[128][65]=8320 | Tt[32][132]=4224
    int t = threadIdx.x;
    int b = blockIdx.y;
    int s0 = blockIdx.x * 128;
    int sl = t & 127, half = t >> 7;
    int cb = half * 32;

    float2 xv = ((const float2*)x)[(size_t)b * SB + s0 + sl];
    float* hcol = h + (size_t)b * WC * SB + s0 + sl;
    #pragma unroll
    for (int c = 0; c < 32; ++c) {
        int ch = cb + c;
        float v = fmaf(xv.x, fc0_w[2 * ch], fmaf(xv.y, fc0_w[2 * ch + 1], fc0_b[ch]));
        hcol[(size_t)ch * SB] = v;
        u[sl * 65 + ch] = v;
    }
    {   // stage T rows [j][132]: Tt[j][s] = T[s0+s][j]
        int sl2 = t >> 1, jj0 = (t & 1) * 16;
        const float4* src = (const float4*)(T + (size_t)(s0 + sl2) * NKC + jj0);
        float4 a = src[0], c4 = src[1], d = src[2], e = src[3];
        float* Tt = u + 8320;
        Tt[(jj0 +  0) * LP + sl2] = a.x;  Tt[(jj0 +  1) * LP + sl2] = a.y;
        Tt[(jj0 +  2) * LP + sl2] = a.z;  Tt[(jj0 +  3) * LP + sl2] = a.w;
        Tt[(jj0 +  4) * LP + sl2] = c4.x; Tt[(jj0 +  5) * LP + sl2] = c4.y;
        Tt[(jj0 +  6) * LP + sl2] = c4.z; Tt[(jj0 +  7) * LP + sl2] = c4.w;
        Tt[(jj0 +  8) * LP + sl2] = d.x;  Tt[(jj0 +  9) * LP + sl2] = d.y;
        Tt[(jj0 + 10) * LP + sl2] = d.z;  Tt[(jj0 + 11) * LP + sl2] = d.w;
        Tt[(jj0 + 12) * LP + sl2] = e.x;  Tt[(jj0 + 13) * LP + sl2] = e.y;
        Tt[(jj0 + 14) * LP + sl2] = e.z;  Tt[(jj0 + 15) * LP + sl2] = e.w;
    }
    __syncthreads();

    int lane = t & 63;
    int wv = __builtin_amdgcn_readfirstlane(t >> 6);
    int g  = lane >> 3;              // ch-group (ch = g*8+i)
    int j8 = lane & 7;               // mode-quad (mode = j8*4+m)

    float dacc[8][4];
    #pragma unroll
    for (int i = 0; i < 8; ++i)
        #pragma unroll
        for (int m = 0; m < 4; ++m) dacc[i][m] = 0.f;

    #pragma unroll 4
    for (int ss = 0; ss < 32; ++ss) {
        int s = wv * 32 + ss;        // wave-uniform -> broadcast reads
        float tv0 = u[8320 + (j8 * 4 + 0) * LP + s];
        float tv1 = u[8320 + (j8 * 4 + 1) * LP + s];
        float tv2 = u[8320 + (j8 * 4 + 2) * LP + s];
        float tv3 = u[8320 + (j8 * 4 + 3) * LP + s];
        float4 h0 = *(const float4*)&u[s * 65 + g * 8];
        float4 h1 = *(const float4*)&u[s * 65 + g * 8 + 4];
        float hh[8] = {h0.x, h0.y, h0.z, h0.w, h1.x, h1.y, h1.z, h1.w};
        #pragma unroll
        for (int i = 0; i < 8; ++i) {
            dacc[i][0] = fmaf(hh[i], tv0, dacc[i][0]);
            dacc[i][1] = fmaf(hh[i], tv1, dacc[i][1]);
            dacc[i][2] = fmaf(hh[i], tv2, dacc[i][2]);
            dacc[i][3] = fmaf(hh[i], tv3, dacc[i][3]);
        }
    }

    __syncthreads();                 // hT2 + T dead; reduce region u[0..8448)
    {
        float* slot = u + (wv * 64 + lane) * 33;
        #pragma unroll
        for (int i = 0; i < 8; ++i)
            #pragma unroll
            for (int m = 0; m < 4; ++m) slot[i * 4 + m] = dacc[i][m];
    }
    __syncthreads();

    float* dst = xfp + ((size_t)(blockIdx.x * NB + b)) * 2048;
    float res[8];
    #pragma unroll
    for (int e = 0; e < 8; ++e) {
        int idx = t * 8 + e;
        int ch = idx >> 5, mode = idx & 31;
        int g2 = ch >> 3, i2 = ch & 7;
        int q2 = mode >> 2, m2 = mode & 3;
        int lane2 = g2 * 8 + q2;
        int v2 = i2 * 4 + m2;
        res[e] = u[lane2 * 33 + v2] + u[(64 + lane2) * 33 + v2]
               + u[(128 + lane2) * 33 + v2] + u[(192 + lane2) * 33 + v2];
    }
    float4* d4 = (float4*)(dst + t * 8);
    d4[0] = make_float4(res[0], res[1], res[2], res[3]);
    d4[1] = make_float4(res[4], res[5], res[6], res[7]);
}

// reduce K-split partials, float4-vectorized (same sc order -> bit-identical).
__global__ __launch_bounds__(256) void k_red(const float* __restrict__ xfp,
                                             float* __restrict__ xf) {
    int idx = blockIdx.x * 256 + threadIdx.x;   // exactly 16384
    int b = idx >> 9;
    int r4 = (idx & 511);                        // float4 index within 2048
    float4 a = make_float4(0.f, 0.f, 0.f, 0.f);
    #pragma unroll 8
    for (int sc = 0; sc < 64; ++sc) {
        float4 v = ((const float4*)(xfp + ((size_t)(sc * NB + b)) * 2048))[r4];
        a.x += v.x; a.y += v.y; a.z += v.z; a.w += v.w;
    }
    ((float4*)(xf + (size_t)b * 2048))[r4] = a;
}

// mode mix (round-21 form): ofT[b][2k][o] = alpha*Re, [2k+1][o] = -alpha*Im
__global__ __launch_bounds__(256) void k_mix(const float* __restrict__ xf,
                                             const float* __restrict__ wr,
                                             const float* __restrict__ wi,
                                             float* __restrict__ ofT) {
    int tid = blockIdx.x * 256 + threadIdx.x;   // exactly 32768
    int k = tid & 15;
    int o = (tid >> 4) & 63;
    int b = tid >> 10;
    float orr = 0.f, oii = 0.f;
    const float2* xfb = (const float2*)(xf + (size_t)b * WC * NKC);
    #pragma unroll 4
    for (int i = 0; i < WC; ++i) {
        float2 cs = xfb[i * NM + k];
        float wrv = wr[(i * WC + o) * NM + k];
        float wiv = wi[(i * WC + o) * NM + k];
        orr = fmaf(cs.x, wrv, fmaf(cs.y, wiv, orr));    // xfr*wr - xfi*wi
        oii = fmaf(cs.x, wiv, fmaf(-cs.y, wrv, oii));   // xfr*wi + xfi*wr
    }
    float alpha = (k == 0 ? 1.f : 2.f) / (float)SB;
    ofT[((size_t)b * NKC + 2 * k) * 64 + o]     = alpha * orr;
    ofT[((size_t)b * NKC + 2 * k + 1) * 64 + o] = -alpha * oii;
}

// fused update (+ forward DFT when dodft) — round-21 form, unchanged.
__global__ __launch_bounds__(256) void k_update(float* __restrict__ h,
                                                const float* __restrict__ T,
                                                const float* __restrict__ ofT,
                                                const float* __restrict__ pwT,
                                                const float* __restrict__ pwb,
                                                int relu, float* __restrict__ xfp,
                                                int dodft) {
    __shared__ float u[8448];      // 33792 B
    float (*hS)[LP] = (float(*)[LP])u;
    int t = threadIdx.x;
    int b = blockIdx.y;
    int s0 = blockIdx.x * 128;
    int lane_s = t & 63;
    int g4 = __builtin_amdgcn_readfirstlane((t >> 6) & 3);
    int ob = g4 * 16;

    {   // stage h[64 ch][128 s]: 4 threads/row, 8 interleaved b128 each
        int ch = t >> 2, part = t & 3;
        const float* hrow = h + ((size_t)(b * WC + ch)) * SB + s0;
        #pragma unroll
        for (int r = 0; r < 8; ++r) {
            int so = (part + 4 * r) * 4;
            *(float4*)&hS[ch][so] = *(const float4*)(hrow + so);
        }
    }
    __syncthreads();

    float acc0[16], acc1[16];
    #pragma unroll
    for (int o = 0; o < 16; ++o) { acc0[o] = pwb[ob + o]; acc1[o] = pwb[ob + o]; }

    const float* wbase0 = pwT + ob;                       // [k][64]
    const float* wbase1 = ofT + ((size_t)b * NKC) * 64 + ob;  // [j][64]

    for (int kc = 0; kc < 8; ++kc) {        // pointwise: k = 0..63
        #pragma unroll
        for (int uu = 0; uu < 8; ++uu) {
            int k = kc * 8 + uu;
            float h0 = hS[k][lane_s];
            float h1 = hS[k][64 + lane_s];
            const float* w = wbase0 + k * 64;
            #pragma unroll
            for (int o = 0; o < 16; ++o) {
                acc0[o] = fmaf(w[o], h0, acc0[o]);
                acc1[o] = fmaf(w[o], h1, acc1[o]);
            }
        }
    }
    // inverse-DFT: T from global (per-thread rows, L2-resident)
    const float4* Trow0 = (const float4*)(T + (size_t)(s0 + lane_s) * NKC);
    const float4* Trow1 = (const float4*)(T + (size_t)(s0 + 64 + lane_s) * NKC);
    for (int kc = 0; kc < 4; ++kc) {
        float4 v0 = Trow0[kc * 2], v1 = Trow0[kc * 2 + 1];
        float4 w0 = Trow1[kc * 2], w1v = Trow1[kc * 2 + 1];
        float xs0[8] = {v0.x, v0.y, v0.z, v0.w, v1.x, v1.y, v1.z, v1.w};
        float xs1[8] = {w0.x, w0.y, w0.z, w0.w, w1v.x, w1v.y, w1v.z, w1v.w};
        #pragma unroll
        for (int uu = 0; uu < 8; ++uu) {
            int j = kc * 8 + uu;
            const float* w = wbase1 + j * 64;
            #pragma unroll
            for (int o = 0; o < 16; ++o) {
                acc0[o] = fmaf(w[o], xs0[uu], acc0[o]);
                acc1[o] = fmaf(w[o], xs1[uu], acc1[o]);
            }
        }
    }

    if (relu) {
        #pragma unroll
        for (int o = 0; o < 16; ++o) {
            acc0[o] = fmaxf(acc0[o], 0.f);
            acc1[o] = fmaxf(acc1[o], 0.f);
        }
    }

    float* hw0 = h + (size_t)b * WC * SB + s0 + lane_s;
    float* hw1 = hw0 + 64;
    #pragma unroll
    for (int o = 0; o < 16; ++o) {
        hw0[(size_t)(ob + o) * SB] = acc0[o];
        hw1[(size_t)(ob + o) * SB] = acc1[o];
    }

    if (!dodft) return;

    // ---- fused forward DFT of the output tile ----
    __syncthreads();                 // all reads of hS done
    #pragma unroll
    for (int o = 0; o < 16; ++o) {
        u[lane_s * 65 + ob + o]        = acc0[o];
        u[(64 + lane_s) * 65 + ob + o] = acc1[o];
    }
    __syncthreads();

    int lane = t & 63;
    int wv = __builtin_amdgcn_readfirstlane(t >> 6);
    int g  = lane >> 3;
    int j8 = lane & 7;

    float dacc[8][4];
    #pragma unroll
    for (int i = 0; i < 8; ++i)
        #pragma unroll
        for (int m = 0; m < 4; ++m) dacc[i][m] = 0.f;

    #pragma unroll 4
    for (int ss = 0; ss < 32; ++ss) {
        int s = wv * 32 + ss;        // wave-uniform row; 8 lanes span 128B (L1-hot)
        float4 tv = *(const float4*)(T + (size_t)(s0 + s) * NKC + j8 * 4);
        float4 h0 = *(const float4*)&u[s * 65 + g * 8];
        float4 h1 = *(const float4*)&u[s * 65 + g * 8 + 4];
        float hh[8] = {h0.x, h0.y, h0.z, h0.w, h1.x, h1.y, h1.z, h1.w};
        #pragma unroll
        for (int i = 0; i < 8; ++i) {
            dacc[i][0] = fmaf(hh[i], tv.x, dacc[i][0]);
            dacc[i][1] = fmaf(hh[i], tv.y, dacc[i][1]);
            dacc[i][2] = fmaf(hh[i], tv.z, dacc[i][2]);
            dacc[i][3] = fmaf(hh[i], tv.w, dacc[i][3]);
        }
    }

    __syncthreads();                 // hT2 dead; reduce region u[0..8448)
    {
        float* slot = u + (wv * 64 + lane) * 33;
        #pragma unroll
        for (int i = 0; i < 8; ++i)
            #pragma unroll
            for (int m = 0; m < 4; ++m) slot[i * 4 + m] = dacc[i][m];
    }
    __syncthreads();

    float* dst = xfp + ((size_t)(blockIdx.x * NB + b)) * 2048;
    float res[8];
    #pragma unroll
    for (int e = 0; e < 8; ++e) {
        int idx = t * 8 + e;
        int ch = idx >> 5, mode = idx & 31;
        int g2 = ch >> 3, i2 = ch & 7;
        int q2 = mode >> 2, m2 = mode & 3;
        int lane2 = g2 * 8 + q2;
        int v2 = i2 * 4 + m2;
        res[e] = u[lane2 * 33 + v2] + u[(64 + lane2) * 33 + v2]
               + u[(128 + lane2) * 33 + v2] + u[(192 + lane2) * 33 + v2];
    }
    float4* d4 = (float4*)(dst + t * 8);
    d4[0] = make_float4(res[0], res[1], res[2], res[3]);
    d4[1] = make_float4(res[4], res[5], res[6], res[7]);
}

// final v4 (round-20 form, kept): 17.4 KB LDS, 2-stage tree combine.
__global__ __launch_bounds__(256) void k_final(const float* __restrict__ h,
                                               const float* __restrict__ fc1_w,
                                               const float* __restrict__ fc1_b,
                                               const float* __restrict__ icaT,
                                               const float* __restrict__ ica_b,
                                               float* __restrict__ out,
                                               float* __restrict__ tc) {
    __shared__ float u_lds[4352];          // 17408 B: hS[64][68]; combine reuses [0..3200)
    float (*hS)[68] = (float(*)[68])u_lds;
    int t = threadIdx.x;
    int b = blockIdx.y;
    int s0 = blockIdx.x * 64;
    int lane_s = t & 63;
    int wv = __builtin_amdgcn_readfirstlane(t >> 6);
    int c0 = wv * 32;

    {   // stage transposed: hS[s][ch] = h[ch][s0+s]
        int sl = t & 63, chg = t >> 6;
        const float* hb = h + (size_t)b * WC * SB + s0 + sl;
        #pragma unroll
        for (int cc = 0; cc < 16; ++cc) {
            int ch = chg * 16 + cc;
            hS[sl][ch] = hb[(size_t)ch * SB];
        }
    }
    __syncthreads();

    float acc[NP];
    #pragma unroll
    for (int p = 0; p < NP; ++p) acc[p] = 0.f;

    for (int cq = 0; cq < 8; ++cq) {
        int c = c0 + 4 * cq;
        float tv0 = fc1_b[c], tv1 = fc1_b[c + 1], tv2 = fc1_b[c + 2], tv3 = fc1_b[c + 3];
        const float* w0 = fc1_w + (size_t)c * WC;
        const float* w1 = w0 + WC;
        const float* w2 = w1 + WC;
        const float* w3 = w2 + WC;
        for (int ioct = 0; ioct < 8; ++ioct) {
            float4 xa = *(const float4*)&hS[lane_s][ioct * 8];
            float4 xb = *(const float4*)&hS[lane_s][ioct * 8 + 4];
            float xsv[8] = {xa.x, xa.y, xa.z, xa.w, xb.x, xb.y, xb.z, xb.w};
            #pragma unroll
            for (int uu = 0; uu < 8; ++uu) {
                int i = ioct * 8 + uu;
                tv0 = fmaf(w0[i], xsv[uu], tv0);
                tv1 = fmaf(w1[i], xsv[uu], tv1);
                tv2 = fmaf(w2[i], xsv[uu], tv2);
                tv3 = fmaf(w3[i], xsv[uu], tv3);
            }
        }
        tv0 = fmaxf(tv0, 0.f); tv1 = fmaxf(tv1, 0.f);
        tv2 = fmaxf(tv2, 0.f); tv3 = fmaxf(tv3, 0.f);
        const float* e0 = icaT + (size_t)c * NP;
        const float* e1 = e0 + NP;
        const float* e2 = e1 + NP;
        const float* e3 = e2 + NP;
        #pragma unroll
        for (int p = 0; p < NP; ++p)
            acc[p] = fmaf(tv0, e0[p], fmaf(tv1, e1[p],
                     fmaf(tv2, e2[p], fmaf(tv3, e3[p], acc[p]))));
    }

    // ---- 2-stage combine in the dead hS region (u_lds[0..3200)) ----
    __syncthreads();                       // hS dead
    if (wv >= 2) {                         // stage 1: waves 2,3 write
        float* slot = u_lds + ((wv - 2) * 64 + lane_s) * 25;
        #pragma unroll
        for (int p = 0; p < NP; ++p) slot[p] = acc[p];
    }
    __syncthreads();
    if (wv < 2) {                          // stage 2: waves 0,1 add partner (wv+2)
        const float* slot = u_lds + (wv * 64 + lane_s) * 25;
        #pragma unroll
        for (int p = 0; p < NP; ++p) acc[p] += slot[p];
    }
    __syncthreads();
    if (wv == 1) {                         // stage 3: wave 1 writes its 2-way sum
        float* slot = u_lds + (64 + lane_s) * 25;
        #pragma unroll
        for (int p = 0; p < NP; ++p) slot[p] = acc[p];
    }
    __syncthreads();
    if (wv == 0) {                         // wave 0: full sum, write tc + out
        const float* slot = u_lds + (64 + lane_s) * 25;
        #pragma unroll
        for (int p = 0; p < NP; ++p) acc[p] += slot[p] + ica_b[p];

        float osum = 0.f;
        #pragma unroll
        for (int p = 0; p < NP; ++p) osum += acc[p];
        size_t idx = (size_t)b * SB + s0 + lane_s;
        out[idx] = osum;

        float4* t4 = (float4*)(tc + idx * NP);   // 96B stride; wave covers 6KB densely
        t4[0] = make_float4(acc[0],  acc[1],  acc[2],  acc[3]);
        t4[1] = make_float4(acc[4],  acc[5],  acc[6],  acc[7]);
        t4[2] = make_float4(acc[8],  acc[9],  acc[10], acc[11]);
        t4[3] = make_float4(acc[12], acc[13], acc[14], acc[15]);
        t4[4] = make_float4(acc[16], acc[17], acc[18], acc[19]);
        t4[5] = make_float4(acc[20], acc[21], acc[22], acc[23]);
    }
}

extern "C" void kernel_launch(void* const* d_in, const int* in_sizes, int n_in,
                              void* d_out, int out_size, void* d_ws, size_t ws_size,
                              hipStream_t stream) {
    const float* x     = (const float*)d_in[0];
    const float* fc0_w = (const float*)d_in[1];
    const float* fc0_b = (const float*)d_in[2];
    const float* cwr   = (const float*)d_in[3];
    const float* cwi   = (const float*)d_in[4];
    const float* pw_w  = (const float*)d_in[5];
    const float* pw_b  = (const float*)d_in[6];
    const float* fc1_w = (const float*)d_in[7];
    const float* fc1_b = (const float*)d_in[8];
    const float* fc2_w = (const float*)d_in[9];
    const float* ica_w = (const float*)d_in[10];
    const float* ica_b = (const float*)d_in[11];

    float* out = (float*)d_out;            // (B,S,1) = 262144
    float* tc  = out + (size_t)NB * SB;    // (B,S,1,24) = 6291456

    float* ws   = (float*)d_ws;
    float* h    = ws;
    float* T    = ws + 16777216;
    float* xf   = ws + 17039360;
    float* ofT  = ws + 17104896;
    float* icaT = ws + 17170432;
    float* pwT  = ws + 17173504;
    float* xfp  = tc;                      // DFT partials scratch (dead until k_final)

    k_table<<<32, 256, 0, stream>>>(T);
    k_prep<<<12, 256, 0, stream>>>(ica_w, fc2_w, icaT);
    k_prepw<<<64, 256, 0, stream>>>(pw_w, pwT);
    k_lift<<<dim3(64, 32), 256, 0, stream>>>(x, fc0_w, fc0_b, h, T, xfp);

    for (int l = 0; l < 4; ++l) {
        k_red<<<64, 256, 0, stream>>>(xfp, xf);
        k_mix<<<128, 256, 0, stream>>>(xf, cwr + (size_t)l * WC * WC * NM,
                                       cwi + (size_t)l * WC * WC * NM, ofT);
        k_update<<<dim3(64, 32), 256, 0, stream>>>(h, T, ofT,
                                                   pwT + (size_t)l * 4096,
                                                   pw_b + (size_t)l * WC,
                                                   (l < 3) ? 1 : 0,
                                                   xfp, (l < 3) ? 1 : 0);
    }

    k_final<<<dim3(128, 32), 256, 0, stream>>>(h, fc1_w, fc1_b, icaT, ica_b, out, tc);
}

// Round 25
// 388.388 us; speedup vs baseline: 1.0091x; 1.0091x over previous
//
#include <hip/hip_runtime.h>
#include <math.h>

#define SB 8192
#define NB 32
#define WC 64
#define NM 16
#define NKC 32   // 2*NM (cos,sin interleaved)
#define NP 24
#define LP 132   // padded LDS row length (128 + 4)

// h layout: h[b][ch][s] (s contiguous)
// ws layout (float offsets):
//   h    : 0         (B*W*S = 16777216)
//   T    : 16777216  (S*32  = 262144)
//   xf   : 17039360  (B*W*32 = 65536)
//   ofT  : 17104896  (B*32*W = 65536)   [j][o] transposed mode weights
//   icaT : 17170432  (128*24 = 3072)
//   pwT  : 17173504  (4*64*64 = 16384)  [l][k][o] transposed pointwise weights
// DFT partials (64 slices x 32 b x 2048) live in the tc output region
// (dead until k_final). All layers produce them fused (lift for l=0,
// update for l=1..3).

__global__ __launch_bounds__(256) void k_table(float* __restrict__ T) {
    int s = blockIdx.x * 256 + threadIdx.x;   // exactly 8192 threads
    float* row = T + (size_t)s * NKC;
    #pragma unroll
    for (int k = 0; k < NM; ++k) {
        int m = (k * s) & (SB - 1);           // exact phase mod S
        double ang = (double)m * (6.283185307179586476925286766559 / (double)SB);
        row[2 * k]     = (float)cos(ang);
        row[2 * k + 1] = (float)sin(ang);
    }
}

// icaT[c][p] = fc2_w[0][c] * ica_w[p][c]
__global__ __launch_bounds__(256) void k_prep(const float* __restrict__ ica_w,
                                              const float* __restrict__ fc2_w,
                                              float* __restrict__ icaT) {
    int tid = blockIdx.x * 256 + threadIdx.x;   // exactly 3072
    int c = tid / NP;
    int p = tid - c * NP;
    icaT[c * NP + p] = ica_w[p * 128 + c] * fc2_w[c];
}

// pwT[l][k][o] = pw_w[l][o][k]
__global__ __launch_bounds__(256) void k_prepw(const float* __restrict__ pw_w,
                                               float* __restrict__ pwT) {
    int tid = blockIdx.x * 256 + threadIdx.x;   // exactly 16384
    int l = tid >> 12, k = (tid >> 6) & 63, o = tid & 63;
    pwT[tid] = pw_w[(size_t)l * 4096 + o * 64 + k];
}

// fused lift + forward DFT (round-21 v1 form: T staged in LDS).
__global__ __launch_bounds__(256) void k_lift(const float* __restrict__ x,
                                              const float* __restrict__ fc0_w,
                                              const float* __restrict__ fc0_b,
                                              float* __restrict__ h,
                                              const float* __restrict__ T,
                                              float* __restrict__ xfp) {
    __shared__ float u[12544];     // 50176 B: hT2[128][65]=8320 | Tt[32][132]=4224
    int t = threadIdx.x;
    int b = blockIdx.y;
    int s0 = blockIdx.x * 128;
    int sl = t & 127, half = t >> 7;
    int cb = half * 32;

    float2 xv = ((const float2*)x)[(size_t)b * SB + s0 + sl];
    float* hcol = h + (size_t)b * WC * SB + s0 + sl;
    #pragma unroll
    for (int c = 0; c < 32; ++c) {
        int ch = cb + c;
        float v = fmaf(xv.x, fc0_w[2 * ch], fmaf(xv.y, fc0_w[2 * ch + 1], fc0_b[ch]));
        hcol[(size_t)ch * SB] = v;
        u[sl * 65 + ch] = v;
    }
    {   // stage T rows [j][132]: Tt[j][s] = T[s0+s][j]
        int sl2 = t >> 1, jj0 = (t & 1) * 16;
        const float4* src = (const float4*)(T + (size_t)(s0 + sl2) * NKC + jj0);
        float4 a = src[0], c4 = src[1], d = src[2], e = src[3];
        float* Tt = u + 8320;
        Tt[(jj0 +  0) * LP + sl2] = a.x;  Tt[(jj0 +  1) * LP + sl2] = a.y;
        Tt[(jj0 +  2) * LP + sl2] = a.z;  Tt[(jj0 +  3) * LP + sl2] = a.w;
        Tt[(jj0 +  4) * LP + sl2] = c4.x; Tt[(jj0 +  5) * LP + sl2] = c4.y;
        Tt[(jj0 +  6) * LP + sl2] = c4.z; Tt[(jj0 +  7) * LP + sl2] = c4.w;
        Tt[(jj0 +  8) * LP + sl2] = d.x;  Tt[(jj0 +  9) * LP + sl2] = d.y;
        Tt[(jj0 + 10) * LP + sl2] = d.z;  Tt[(jj0 + 11) * LP + sl2] = d.w;
        Tt[(jj0 + 12) * LP + sl2] = e.x;  Tt[(jj0 + 13) * LP + sl2] = e.y;
        Tt[(jj0 + 14) * LP + sl2] = e.z;  Tt[(jj0 + 15) * LP + sl2] = e.w;
    }
    __syncthreads();

    int lane = t & 63;
    int wv = __builtin_amdgcn_readfirstlane(t >> 6);
    int g  = lane >> 3;              // ch-group (ch = g*8+i)
    int j8 = lane & 7;               // mode-quad (mode = j8*4+m)

    float dacc[8][4];
    #pragma unroll
    for (int i = 0; i < 8; ++i)
        #pragma unroll
        for (int m = 0; m < 4; ++m) dacc[i][m] = 0.f;

    #pragma unroll 4
    for (int ss = 0; ss < 32; ++ss) {
        int s = wv * 32 + ss;        // wave-uniform -> broadcast reads
        float tv0 = u[8320 + (j8 * 4 + 0) * LP + s];
        float tv1 = u[8320 + (j8 * 4 + 1) * LP + s];
        float tv2 = u[8320 + (j8 * 4 + 2) * LP + s];
        float tv3 = u[8320 + (j8 * 4 + 3) * LP + s];
        float4 h0 = *(const float4*)&u[s * 65 + g * 8];
        float4 h1 = *(const float4*)&u[s * 65 + g * 8 + 4];
        float hh[8] = {h0.x, h0.y, h0.z, h0.w, h1.x, h1.y, h1.z, h1.w};
        #pragma unroll
        for (int i = 0; i < 8; ++i) {
            dacc[i][0] = fmaf(hh[i], tv0, dacc[i][0]);
            dacc[i][1] = fmaf(hh[i], tv1, dacc[i][1]);
            dacc[i][2] = fmaf(hh[i], tv2, dacc[i][2]);
            dacc[i][3] = fmaf(hh[i], tv3, dacc[i][3]);
        }
    }

    __syncthreads();                 // hT2 + T dead; reduce region u[0..8448)
    {
        float* slot = u + (wv * 64 + lane) * 33;
        #pragma unroll
        for (int i = 0; i < 8; ++i)
            #pragma unroll
            for (int m = 0; m < 4; ++m) slot[i * 4 + m] = dacc[i][m];
    }
    __syncthreads();

    float* dst = xfp + ((size_t)(blockIdx.x * NB + b)) * 2048;
    float res[8];
    #pragma unroll
    for (int e = 0; e < 8; ++e) {
        int idx = t * 8 + e;
        int ch = idx >> 5, mode = idx & 31;
        int g2 = ch >> 3, i2 = ch & 7;
        int q2 = mode >> 2, m2 = mode & 3;
        int lane2 = g2 * 8 + q2;
        int v2 = i2 * 4 + m2;
        res[e] = u[lane2 * 33 + v2] + u[(64 + lane2) * 33 + v2]
               + u[(128 + lane2) * 33 + v2] + u[(192 + lane2) * 33 + v2];
    }
    float4* d4 = (float4*)(dst + t * 8);
    d4[0] = make_float4(res[0], res[1], res[2], res[3]);
    d4[1] = make_float4(res[4], res[5], res[6], res[7]);
}

// reduce K-split partials (round-21 form: 256 blocks, full-machine spread)
__global__ __launch_bounds__(256) void k_red(const float* __restrict__ xfp,
                                             float* __restrict__ xf) {
    int idx = blockIdx.x * 256 + threadIdx.x;   // exactly 65536
    int b = idx >> 11;
    int r = idx & 2047;
    float s = 0.f;
    #pragma unroll 8
    for (int sc = 0; sc < 64; ++sc)
        s += xfp[((size_t)(sc * NB + b)) * 2048 + r];
    xf[idx] = s;
}

// mode mix (round-21 form): ofT[b][2k][o] = alpha*Re, [2k+1][o] = -alpha*Im
__global__ __launch_bounds__(256) void k_mix(const float* __restrict__ xf,
                                             const float* __restrict__ wr,
                                             const float* __restrict__ wi,
                                             float* __restrict__ ofT) {
    int tid = blockIdx.x * 256 + threadIdx.x;   // exactly 32768
    int k = tid & 15;
    int o = (tid >> 4) & 63;
    int b = tid >> 10;
    float orr = 0.f, oii = 0.f;
    const float2* xfb = (const float2*)(xf + (size_t)b * WC * NKC);
    #pragma unroll 4
    for (int i = 0; i < WC; ++i) {
        float2 cs = xfb[i * NM + k];
        float wrv = wr[(i * WC + o) * NM + k];
        float wiv = wi[(i * WC + o) * NM + k];
        orr = fmaf(cs.x, wrv, fmaf(cs.y, wiv, orr));    // xfr*wr - xfi*wi
        oii = fmaf(cs.x, wiv, fmaf(-cs.y, wrv, oii));   // xfr*wi + xfi*wr
    }
    float alpha = (k == 0 ? 1.f : 2.f) / (float)SB;
    ofT[((size_t)b * NKC + 2 * k) * 64 + o]     = alpha * orr;
    ofT[((size_t)b * NKC + 2 * k + 1) * 64 + o] = -alpha * oii;
}

// fused update (+ forward DFT when dodft) — round-21 form, unchanged.
__global__ __launch_bounds__(256) void k_update(float* __restrict__ h,
                                                const float* __restrict__ T,
                                                const float* __restrict__ ofT,
                                                const float* __restrict__ pwT,
                                                const float* __restrict__ pwb,
                                                int relu, float* __restrict__ xfp,
                                                int dodft) {
    __shared__ float u[8448];      // 33792 B
    float (*hS)[LP] = (float(*)[LP])u;
    int t = threadIdx.x;
    int b = blockIdx.y;
    int s0 = blockIdx.x * 128;
    int lane_s = t & 63;
    int g4 = __builtin_amdgcn_readfirstlane((t >> 6) & 3);
    int ob = g4 * 16;

    {   // stage h[64 ch][128 s]: 4 threads/row, 8 interleaved b128 each
        int ch = t >> 2, part = t & 3;
        const float* hrow = h + ((size_t)(b * WC + ch)) * SB + s0;
        #pragma unroll
        for (int r = 0; r < 8; ++r) {
            int so = (part + 4 * r) * 4;
            *(float4*)&hS[ch][so] = *(const float4*)(hrow + so);
        }
    }
    __syncthreads();

    float acc0[16], acc1[16];
    #pragma unroll
    for (int o = 0; o < 16; ++o) { acc0[o] = pwb[ob + o]; acc1[o] = pwb[ob + o]; }

    const float* wbase0 = pwT + ob;                       // [k][64]
    const float* wbase1 = ofT + ((size_t)b * NKC) * 64 + ob;  // [j][64]

    for (int kc = 0; kc < 8; ++kc) {        // pointwise: k = 0..63
        #pragma unroll
        for (int uu = 0; uu < 8; ++uu) {
            int k = kc * 8 + uu;
            float h0 = hS[k][lane_s];
            float h1 = hS[k][64 + lane_s];
            const float* w = wbase0 + k * 64;
            #pragma unroll
            for (int o = 0; o < 16; ++o) {
                acc0[o] = fmaf(w[o], h0, acc0[o]);
                acc1[o] = fmaf(w[o], h1, acc1[o]);
            }
        }
    }
    // inverse-DFT: T from global (per-thread rows, L2-resident)
    const float4* Trow0 = (const float4*)(T + (size_t)(s0 + lane_s) * NKC);
    const float4* Trow1 = (const float4*)(T + (size_t)(s0 + 64 + lane_s) * NKC);
    for (int kc = 0; kc < 4; ++kc) {
        float4 v0 = Trow0[kc * 2], v1 = Trow0[kc * 2 + 1];
        float4 w0 = Trow1[kc * 2], w1v = Trow1[kc * 2 + 1];
        float xs0[8] = {v0.x, v0.y, v0.z, v0.w, v1.x, v1.y, v1.z, v1.w};
        float xs1[8] = {w0.x, w0.y, w0.z, w0.w, w1v.x, w1v.y, w1v.z, w1v.w};
        #pragma unroll
        for (int uu = 0; uu < 8; ++uu) {
            int j = kc * 8 + uu;
            const float* w = wbase1 + j * 64;
            #pragma unroll
            for (int o = 0; o < 16; ++o) {
                acc0[o] = fmaf(w[o], xs0[uu], acc0[o]);
                acc1[o] = fmaf(w[o], xs1[uu], acc1[o]);
            }
        }
    }

    if (relu) {
        #pragma unroll
        for (int o = 0; o < 16; ++o) {
            acc0[o] = fmaxf(acc0[o], 0.f);
            acc1[o] = fmaxf(acc1[o], 0.f);
        }
    }

    float* hw0 = h + (size_t)b * WC * SB + s0 + lane_s;
    float* hw1 = hw0 + 64;
    #pragma unroll
    for (int o = 0; o < 16; ++o) {
        hw0[(size_t)(ob + o) * SB] = acc0[o];
        hw1[(size_t)(ob + o) * SB] = acc1[o];
    }

    if (!dodft) return;

    // ---- fused forward DFT of the output tile ----
    __syncthreads();                 // all reads of hS done
    #pragma unroll
    for (int o = 0; o < 16; ++o) {
        u[lane_s * 65 + ob + o]        = acc0[o];
        u[(64 + lane_s) * 65 + ob + o] = acc1[o];
    }
    __syncthreads();

    int lane = t & 63;
    int wv = __builtin_amdgcn_readfirstlane(t >> 6);
    int g  = lane >> 3;
    int j8 = lane & 7;

    float dacc[8][4];
    #pragma unroll
    for (int i = 0; i < 8; ++i)
        #pragma unroll
        for (int m = 0; m < 4; ++m) dacc[i][m] = 0.f;

    #pragma unroll 4
    for (int ss = 0; ss < 32; ++ss) {
        int s = wv * 32 + ss;        // wave-uniform row; 8 lanes span 128B (L1-hot)
        float4 tv = *(const float4*)(T + (size_t)(s0 + s) * NKC + j8 * 4);
        float4 h0 = *(const float4*)&u[s * 65 + g * 8];
        float4 h1 = *(const float4*)&u[s * 65 + g * 8 + 4];
        float hh[8] = {h0.x, h0.y, h0.z, h0.w, h1.x, h1.y, h1.z, h1.w};
        #pragma unroll
        for (int i = 0; i < 8; ++i) {
            dacc[i][0] = fmaf(hh[i], tv.x, dacc[i][0]);
            dacc[i][1] = fmaf(hh[i], tv.y, dacc[i][1]);
            dacc[i][2] = fmaf(hh[i], tv.z, dacc[i][2]);
            dacc[i][3] = fmaf(hh[i], tv.w, dacc[i][3]);
        }
    }

    __syncthreads();                 // hT2 dead; reduce region u[0..8448)
    {
        float* slot = u + (wv * 64 + lane) * 33;
        #pragma unroll
        for (int i = 0; i < 8; ++i)
            #pragma unroll
            for (int m = 0; m < 4; ++m) slot[i * 4 + m] = dacc[i][m];
    }
    __syncthreads();

    float* dst = xfp + ((size_t)(blockIdx.x * NB + b)) * 2048;
    float res[8];
    #pragma unroll
    for (int e = 0; e < 8; ++e) {
        int idx = t * 8 + e;
        int ch = idx >> 5, mode = idx & 31;
        int g2 = ch >> 3, i2 = ch & 7;
        int q2 = mode >> 2, m2 = mode & 3;
        int lane2 = g2 * 8 + q2;
        int v2 = i2 * 4 + m2;
        res[e] = u[lane2 * 33 + v2] + u[(64 + lane2) * 33 + v2]
               + u[(128 + lane2) * 33 + v2] + u[(192 + lane2) * 33 + v2];
    }
    float4* d4 = (float4*)(dst + t * 8);
    d4[0] = make_float4(res[0], res[1], res[2], res[3]);
    d4[1] = make_float4(res[4], res[5], res[6], res[7]);
}

// final v4 (round-20 form, kept): 17.4 KB LDS, 2-stage tree combine.
__global__ __launch_bounds__(256) void k_final(const float* __restrict__ h,
                                               const float* __restrict__ fc1_w,
                                               const float* __restrict__ fc1_b,
                                               const float* __restrict__ icaT,
                                               const float* __restrict__ ica_b,
                                               float* __restrict__ out,
                                               float* __restrict__ tc) {
    __shared__ float u_lds[4352];          // 17408 B: hS[64][68]; combine reuses [0..3200)
    float (*hS)[68] = (float(*)[68])u_lds;
    int t = threadIdx.x;
    int b = blockIdx.y;
    int s0 = blockIdx.x * 64;
    int lane_s = t & 63;
    int wv = __builtin_amdgcn_readfirstlane(t >> 6);
    int c0 = wv * 32;

    {   // stage transposed: hS[s][ch] = h[ch][s0+s]
        int sl = t & 63, chg = t >> 6;
        const float* hb = h + (size_t)b * WC * SB + s0 + sl;
        #pragma unroll
        for (int cc = 0; cc < 16; ++cc) {
            int ch = chg * 16 + cc;
            hS[sl][ch] = hb[(size_t)ch * SB];
        }
    }
    __syncthreads();

    float acc[NP];
    #pragma unroll
    for (int p = 0; p < NP; ++p) acc[p] = 0.f;

    for (int cq = 0; cq < 8; ++cq) {
        int c = c0 + 4 * cq;
        float tv0 = fc1_b[c], tv1 = fc1_b[c + 1], tv2 = fc1_b[c + 2], tv3 = fc1_b[c + 3];
        const float* w0 = fc1_w + (size_t)c * WC;
        const float* w1 = w0 + WC;
        const float* w2 = w1 + WC;
        const float* w3 = w2 + WC;
        for (int ioct = 0; ioct < 8; ++ioct) {
            float4 xa = *(const float4*)&hS[lane_s][ioct * 8];
            float4 xb = *(const float4*)&hS[lane_s][ioct * 8 + 4];
            float xsv[8] = {xa.x, xa.y, xa.z, xa.w, xb.x, xb.y, xb.z, xb.w};
            #pragma unroll
            for (int uu = 0; uu < 8; ++uu) {
                int i = ioct * 8 + uu;
                tv0 = fmaf(w0[i], xsv[uu], tv0);
                tv1 = fmaf(w1[i], xsv[uu], tv1);
                tv2 = fmaf(w2[i], xsv[uu], tv2);
                tv3 = fmaf(w3[i], xsv[uu], tv3);
            }
        }
        tv0 = fmaxf(tv0, 0.f); tv1 = fmaxf(tv1, 0.f);
        tv2 = fmaxf(tv2, 0.f); tv3 = fmaxf(tv3, 0.f);
        const float* e0 = icaT + (size_t)c * NP;
        const float* e1 = e0 + NP;
        const float* e2 = e1 + NP;
        const float* e3 = e2 + NP;
        #pragma unroll
        for (int p = 0; p < NP; ++p)
            acc[p] = fmaf(tv0, e0[p], fmaf(tv1, e1[p],
                     fmaf(tv2, e2[p], fmaf(tv3, e3[p], acc[p]))));
    }

    // ---- 2-stage combine in the dead hS region (u_lds[0..3200)) ----
    __syncthreads();                       // hS dead
    if (wv >= 2) {                         // stage 1: waves 2,3 write
        float* slot = u_lds + ((wv - 2) * 64 + lane_s) * 25;
        #pragma unroll
        for (int p = 0; p < NP; ++p) slot[p] = acc[p];
    }
    __syncthreads();
    if (wv < 2) {                          // stage 2: waves 0,1 add partner (wv+2)
        const float* slot = u_lds + (wv * 64 + lane_s) * 25;
        #pragma unroll
        for (int p = 0; p < NP; ++p) acc[p] += slot[p];
    }
    __syncthreads();
    if (wv == 1) {                         // stage 3: wave 1 writes its 2-way sum
        float* slot = u_lds + (64 + lane_s) * 25;
        #pragma unroll
        for (int p = 0; p < NP; ++p) slot[p] = acc[p];
    }
    __syncthreads();
    if (wv == 0) {                         // wave 0: full sum, write tc + out
        const float* slot = u_lds + (64 + lane_s) * 25;
        #pragma unroll
        for (int p = 0; p < NP; ++p) acc[p] += slot[p] + ica_b[p];

        float osum = 0.f;
        #pragma unroll
        for (int p = 0; p < NP; ++p) osum += acc[p];
        size_t idx = (size_t)b * SB + s0 + lane_s;
        out[idx] = osum;

        float4* t4 = (float4*)(tc + idx * NP);   // 96B stride; wave covers 6KB densely
        t4[0] = make_float4(acc[0],  acc[1],  acc[2],  acc[3]);
        t4[1] = make_float4(acc[4],  acc[5],  acc[6],  acc[7]);
        t4[2] = make_float4(acc[8],  acc[9],  acc[10], acc[11]);
        t4[3] = make_float4(acc[12], acc[13], acc[14], acc[15]);
        t4[4] = make_float4(acc[16], acc[17], acc[18], acc[19]);
        t4[5] = make_float4(acc[20], acc[21], acc[22], acc[23]);
    }
}

extern "C" void kernel_launch(void* const* d_in, const int* in_sizes, int n_in,
                              void* d_out, int out_size, void* d_ws, size_t ws_size,
                              hipStream_t stream) {
    const float* x     = (const float*)d_in[0];
    const float* fc0_w = (const float*)d_in[1];
    const float* fc0_b = (const float*)d_in[2];
    const float* cwr   = (const float*)d_in[3];
    const float* cwi   = (const float*)d_in[4];
    const float* pw_w  = (const float*)d_in[5];
    const float* pw_b  = (const float*)d_in[6];
    const float* fc1_w = (const float*)d_in[7];
    const float* fc1_b = (const float*)d_in[8];
    const float* fc2_w = (const float*)d_in[9];
    const float* ica_w = (const float*)d_in[10];
    const float* ica_b = (const float*)d_in[11];

    float* out = (float*)d_out;            // (B,S,1) = 262144
    float* tc  = out + (size_t)NB * SB;    // (B,S,1,24) = 6291456

    float* ws   = (float*)d_ws;
    float* h    = ws;
    float* T    = ws + 16777216;
    float* xf   = ws + 17039360;
    float* ofT  = ws + 17104896;
    float* icaT = ws + 17170432;
    float* pwT  = ws + 17173504;
    float* xfp  = tc;                      // DFT partials scratch (dead until k_final)

    k_table<<<32, 256, 0, stream>>>(T);
    k_prep<<<12, 256, 0, stream>>>(ica_w, fc2_w, icaT);
    k_prepw<<<64, 256, 0, stream>>>(pw_w, pwT);
    k_lift<<<dim3(64, 32), 256, 0, stream>>>(x, fc0_w, fc0_b, h, T, xfp);

    for (int l = 0; l < 4; ++l) {
        k_red<<<256, 256, 0, stream>>>(xfp, xf);
        k_mix<<<128, 256, 0, stream>>>(xf, cwr + (size_t)l * WC * WC * NM,
                                       cwi + (size_t)l * WC * WC * NM, ofT);
        k_update<<<dim3(64, 32), 256, 0, stream>>>(h, T, ofT,
                                                   pwT + (size_t)l * 4096,
                                                   pw_b + (size_t)l * WC,
                                                   (l < 3) ? 1 : 0,
                                                   xfp, (l < 3) ? 1 : 0);
    }

    k_final<<<dim3(128, 32), 256, 0, stream>>>(h, fc1_w, fc1_b, icaT, ica_b, out, tc);
}